// Round 7
// baseline (218.856 us; speedup 1.0000x reference)
//
#include <hip/hip_runtime.h>
#include <hip/hip_bf16.h>
#include <cmath>

// ---------------------------------------------------------------------------
// DistanceAwareSelfAttentionHead — bf16 MFMA, round 7.
//   - PV: split-K NZ=4, 128^2 tiles, 512 blocks (2/CU — proven R3/R5);
//     reduce FUSED into PV via last-block counter protocol (deterministic:
//     fixed z-order sum), rank-2 epilogue included. No reduce kernel.
//   - prep: coalesced 32x32 LDS-tiled weight transposes (+ counter zeroing).
//   - Ledger: split-K accumulation must be partials+ordered reduce, NOT
//     atomics (R6: +28us). This 2-phase GEMM needs >=2 blocks/CU (R4).
//   8 kernel launches.
// ---------------------------------------------------------------------------

typedef short bf16x8 __attribute__((ext_vector_type(8)));
typedef float f32x4  __attribute__((ext_vector_type(4)));
typedef unsigned short ushort_t;
typedef unsigned short ushort4v __attribute__((ext_vector_type(4)));
typedef unsigned short ushort8v __attribute__((ext_vector_type(8)));

__device__ __forceinline__ ushort_t f2bf(float f) {
    union { float f; unsigned u; } v; v.f = f;
    unsigned u = v.u;
    u += 0x7FFFu + ((u >> 16) & 1u);   // RNE
    return (ushort_t)(u >> 16);
}
__device__ __forceinline__ float bf2f(ushort_t h) {
    union { unsigned u; float f; } v; v.u = ((unsigned)h) << 16;
    return v.f;
}
__device__ __forceinline__ void gload_lds16(const void* g, void* l) {
    __builtin_amdgcn_global_load_lds(
        (const __attribute__((address_space(1))) void*)g,
        (__attribute__((address_space(3))) void*)l, 16, 0, 0);
}

// ---------------------------------------------------------------------------
// 128x128x(BK=32) NT GEMM core: acc[i][j] = sum_k A[bm..][k] * B[bn..][k]
// ---------------------------------------------------------------------------
__device__ __forceinline__ void gemm_core(
    const ushort_t* __restrict__ A, const ushort_t* __restrict__ B,
    int lda, int ldb, int Ksz, size_t kbase, int bm, int bn,
    ushort_t* As, ushort_t* Bs, f32x4 (&acc)[4][4])
{
    constexpr int BK = 32;
    const int tid  = threadIdx.x;
    const int lane = tid & 63;
    const int wid  = tid >> 6;
    const int wm = (wid >> 1) * 64;
    const int wn = (wid & 1) * 64;

    const int r0 = tid >> 2;
    const int c8 = (tid & 3) * 8;
    const ushort_t* Ag0 = A + (size_t)(bm + r0) * lda + kbase + c8;
    const ushort_t* Bg0 = B + (size_t)(bn + r0) * ldb + kbase + c8;
    const ushort_t* Ag1 = Ag0 + (size_t)64 * lda;
    const ushort_t* Bg1 = Bg0 + (size_t)64 * ldb;
    ushort_t* AsW0 = &As[(wid * 64) * 8];
    ushort_t* AsW1 = &As[(256 + wid * 64) * 8];
    ushort_t* BsW0 = &Bs[(wid * 64) * 8];
    ushort_t* BsW1 = &Bs[(256 + wid * 64) * 8];

    const int fr = lane & 15;
    const int kh = (lane >> 4) * 8;

    for (int k0 = 0; k0 < Ksz; k0 += BK) {
        gload_lds16(Ag0 + k0, AsW0);
        gload_lds16(Ag1 + k0, AsW1);
        gload_lds16(Bg0 + k0, BsW0);
        gload_lds16(Bg1 + k0, BsW1);
        __syncthreads();

        bf16x8 af[4], bfv[4];
        #pragma unroll
        for (int i = 0; i < 4; ++i) {
            af[i]  = *(const bf16x8*)&As[(wm + i * 16 + fr) * 32 + kh];
            bfv[i] = *(const bf16x8*)&Bs[(wn + i * 16 + fr) * 32 + kh];
        }
        #pragma unroll
        for (int i = 0; i < 4; ++i)
            #pragma unroll
            for (int j = 0; j < 4; ++j)
                acc[i][j] = __builtin_amdgcn_mfma_f32_16x16x32_bf16(
                    af[i], bfv[j], acc[i][j], 0, 0, 0);
        __syncthreads();
    }
}

__device__ __forceinline__ int swizzle_bid()
{
    int bid = blockIdx.y * gridDim.x + blockIdx.x;
    const int nwg = gridDim.x * gridDim.y;
    if ((nwg & 7) == 0) {
        const int cpx = nwg >> 3;
        bid = (bid & 7) * cpx + (bid >> 3);
    }
    return bid;
}

// general 128x128 GEMM (f32 or bf16 store) — used for S logits GEMM
template<bool STORE_BF16>
__global__ __launch_bounds__(256) void gemm_nt_mfma(
    const ushort_t* __restrict__ A, const ushort_t* __restrict__ B,
    void* __restrict__ Cv, int lda, int ldb, int ldc, int Ksz, float alpha)
{
    __shared__ ushort_t As[128 * 32];
    __shared__ ushort_t Bs[128 * 32];
    const int bid = swizzle_bid();
    const int bm = (bid / gridDim.x) * 128;
    const int bn = (bid % gridDim.x) * 128;
    f32x4 acc[4][4] = {};
    gemm_core(A, B, lda, ldb, Ksz, 0, bm, bn, As, Bs, acc);

    const int lane = threadIdx.x & 63;
    const int wid  = threadIdx.x >> 6;
    const int wm = (wid >> 1) * 64, wn = (wid & 1) * 64;
    const int cr = (lane >> 4) * 4, cc = lane & 15;
    #pragma unroll
    for (int i = 0; i < 4; ++i)
        #pragma unroll
        for (int j = 0; j < 4; ++j) {
            const int col = bn + wn + j * 16 + cc;
            const int rowb = bm + wm + i * 16 + cr;
            #pragma unroll
            for (int jj = 0; jj < 4; ++jj) {
                const float val = alpha * acc[i][j][jj];
                if (STORE_BF16)
                    ((ushort_t*)Cv)[(size_t)(rowb + jj) * ldc + col] = f2bf(val);
                else
                    ((float*)Cv)[(size_t)(rowb + jj) * ldc + col] = val;
            }
        }
}

// both projections in one launch (256 blocks)
__global__ __launch_bounds__(256) void proj_gemm(
    const ushort_t* __restrict__ xb, const ushort_t* __restrict__ Wqkt,
    const ushort_t* __restrict__ Wvt, ushort_t* __restrict__ qkb,
    ushort_t* __restrict__ vTb, int FEAT, int HID, int N)
{
    __shared__ ushort_t As[128 * 32];
    __shared__ ushort_t Bs[128 * 32];
    const int b = blockIdx.x;
    const ushort_t* A; const ushort_t* B; ushort_t* C;
    int bm, bn, ldc;
    if (b < 128) {
        const int gx = (2 * HID) / 128;              // 4
        bm = (b / gx) * 128; bn = (b % gx) * 128;
        A = xb; B = Wqkt; C = qkb; ldc = 2 * HID;
    } else {
        const int b2 = b - 128;
        const int gx = N / 128;                      // 32
        bm = (b2 / gx) * 128; bn = (b2 % gx) * 128;
        A = Wvt; B = xb; C = vTb; ldc = N;
    }
    f32x4 acc[4][4] = {};
    gemm_core(A, B, FEAT, FEAT, FEAT, 0, bm, bn, As, Bs, acc);

    const int lane = threadIdx.x & 63;
    const int wid  = threadIdx.x >> 6;
    const int wm = (wid >> 1) * 64, wn = (wid & 1) * 64;
    const int cr = (lane >> 4) * 4, cc = lane & 15;
    #pragma unroll
    for (int i = 0; i < 4; ++i)
        #pragma unroll
        for (int j = 0; j < 4; ++j) {
            const int col = bn + wn + j * 16 + cc;
            const int rowb = bm + wm + i * 16 + cr;
            #pragma unroll
            for (int jj = 0; jj < 4; ++jj)
                C[(size_t)(rowb + jj) * ldc + col] = f2bf(acc[i][j][jj]);
        }
}

// ---------------------------------------------------------------------------
// PV split-K with fused last-block reduce:
//   parts[z] = P[:, zK:(z+1)K] @ vT^T; last block per tile sums z=0..3 in
//   fixed order + rank-2 term -> out. Deterministic.
// Grid (FEAT/128, N/128, NZ) = (4, 32, 4) = 512 blocks.
// ---------------------------------------------------------------------------
__global__ __launch_bounds__(256) void pv_gemm_splitk(
    const ushort_t* __restrict__ P, const ushort_t* __restrict__ vT,
    float* __restrict__ parts, float* __restrict__ out,
    const float* __restrict__ c0, const float* __restrict__ c1,
    const float* __restrict__ Ev, int* __restrict__ counters,
    int N, int FEAT, int Kchunk, int NZ)
{
    __shared__ ushort_t As[128 * 32];
    __shared__ ushort_t Bs[128 * 32];
    const int bid = swizzle_bid();
    const int bm = (bid / gridDim.x) * 128;   // row tile in [0,N)
    const int bn = (bid % gridDim.x) * 128;   // col tile in [0,FEAT)
    const size_t zs = (size_t)N * FEAT;

    f32x4 acc[4][4] = {};
    gemm_core(P, vT, N, N, Kchunk, (size_t)blockIdx.z * Kchunk, bm, bn, As, Bs, acc);

    // store partial
    const int tid = threadIdx.x;
    const int lane = tid & 63;
    const int wid  = tid >> 6;
    const int wm = (wid >> 1) * 64, wn = (wid & 1) * 64;
    const int cr = (lane >> 4) * 4, cc = lane & 15;
    float* myPart = parts + (size_t)blockIdx.z * zs;
    #pragma unroll
    for (int i = 0; i < 4; ++i)
        #pragma unroll
        for (int j = 0; j < 4; ++j) {
            const int col = bn + wn + j * 16 + cc;
            const int rowb = bm + wm + i * 16 + cr;
            #pragma unroll
            for (int jj = 0; jj < 4; ++jj)
                myPart[(size_t)(rowb + jj) * FEAT + col] = acc[i][j][jj];
        }

    // last-arriving block per tile reduces (fixed z order -> deterministic)
    __threadfence();                    // make partial visible device-wide
    const int tileid = (bm >> 7) * gridDim.x + (bn >> 7);
    __shared__ int ticket;
    if (tid == 0) ticket = atomicAdd(&counters[tileid], 1);
    __syncthreads();
    if (ticket != NZ - 1) return;
    __threadfence();                    // acquire: see other blocks' partials

    // 256 threads cover the 128x128 tile: thread t -> row bm+(t>>1),
    // 64-col half (t&1); 16 float4 per thread.
    const int r  = bm + (tid >> 1);
    const int cb = bn + (tid & 1) * 64;
    const float a0 = c0[r], a1 = c1[r];
    #pragma unroll 4
    for (int c4 = 0; c4 < 16; ++c4) {
        const int col = cb + c4 * 4;
        const size_t off = (size_t)r * FEAT + col;
        float4 s = *(const float4*)(parts + off);
        for (int z = 1; z < NZ; ++z) {
            const float4 p = *(const float4*)(parts + (size_t)z * zs + off);
            s.x += p.x; s.y += p.y; s.z += p.z; s.w += p.w;
        }
        const float4 e0 = *(const float4*)(Ev + col);
        const float4 e1 = *(const float4*)(Ev + FEAT + col);
        s.x += a0 * e0.x + a1 * e1.x;
        s.y += a0 * e0.y + a1 * e1.y;
        s.z += a0 * e0.z + a1 * e1.z;
        s.w += a0 * e0.w + a1 * e1.w;
        *(float4*)(out + off) = s;
    }
}

// ---------------------------------------------------------------------------
// prep: xb = bf16(x) (vectorized); W transposes via coalesced 32x32 LDS tiles;
// zero the split-K counters.
// Block layout: [0, xBlocks) x-convert; then 128 Wq tiles, 128 Wk tiles,
// 256 Wv tiles.
__global__ __launch_bounds__(256) void prep_kernel(
    const float* __restrict__ x, const float* __restrict__ Wq,
    const float* __restrict__ Wk, const float* __restrict__ Wv,
    ushort_t* __restrict__ xb, ushort_t* __restrict__ Wqkt,
    ushort_t* __restrict__ Wvt, int* __restrict__ counters,
    int N, int FEAT, int HID)
{
    const int b = blockIdx.x;
    const int tid = threadIdx.x;
    if (b == 0 && tid < 128) counters[tid] = 0;

    const int xBlocks = (N * FEAT / 8) / 256;              // 1024
    if (b < xBlocks) {
        const int i = b * 256 + tid;
        const float4 a = ((const float4*)x)[2 * i];
        const float4 c = ((const float4*)x)[2 * i + 1];
        ushort8v o;
        o[0] = f2bf(a.x); o[1] = f2bf(a.y); o[2] = f2bf(a.z); o[3] = f2bf(a.w);
        o[4] = f2bf(c.x); o[5] = f2bf(c.y); o[6] = f2bf(c.z); o[7] = f2bf(c.w);
        ((ushort8v*)xb)[i] = o;
        return;
    }

    // tiled transpose src[I][O] -> dst[O][I], 32x32 tiles
    __shared__ float tile[32][33];
    const int qkTiles = (FEAT / 32) * (HID / 32);          // 128
    int t = b - xBlocks;
    const float* src; ushort_t* dst; int I, O;
    if (t < qkTiles)            { src = Wq; dst = Wqkt;                       I = FEAT; O = HID; }
    else if (t < 2 * qkTiles)   { src = Wk; dst = Wqkt + (size_t)HID * FEAT;  I = FEAT; O = HID; t -= qkTiles; }
    else                        { src = Wv; dst = Wvt;                        I = FEAT; O = FEAT; t -= 2 * qkTiles; }
    const int ot = O / 32;
    const int r0 = (t / ot) * 32;   // i-offset
    const int c0 = (t % ot) * 32;   // o-offset
    const int lr = tid >> 5;        // 0..7
    const int lc = tid & 31;        // 0..31
    #pragma unroll
    for (int rr = 0; rr < 32; rr += 8)
        tile[lr + rr][lc] = src[(size_t)(r0 + lr + rr) * O + c0 + lc];
    __syncthreads();
    #pragma unroll
    for (int rr = 0; rr < 32; rr += 8)
        dst[(size_t)(c0 + lr + rr) * I + r0 + lc] = f2bf(tile[lc][lr + rr]);
}

// per-node dots from merged qk buffer; also zeroes c0/c1
__global__ __launch_bounds__(256) void node_dots(
    const ushort_t* __restrict__ qk,
    const float* __restrict__ Ek, const float* __restrict__ Eq,
    float* qk0, float* qk1, float* kq0, float* kq1,
    float* c0, float* c1, int HID)
{
    const int node = blockIdx.x;
    const int t = threadIdx.x;   // == HID == 256
    const ushort_t* row = qk + (size_t)node * (2 * HID);
    const float qv = bf2f(row[t]);
    const float kv = bf2f(row[HID + t]);
    float p0 = qv * Ek[t];
    float p1 = qv * Ek[HID + t];
    float p2 = kv * Eq[t];
    float p3 = kv * Eq[HID + t];
    #pragma unroll
    for (int off = 32; off > 0; off >>= 1) {
        p0 += __shfl_down(p0, off);
        p1 += __shfl_down(p1, off);
        p2 += __shfl_down(p2, off);
        p3 += __shfl_down(p3, off);
    }
    __shared__ float red[4][4];
    if ((t & 63) == 0) {
        const int w = t >> 6;
        red[w][0] = p0; red[w][1] = p1; red[w][2] = p2; red[w][3] = p3;
    }
    __syncthreads();
    if (t == 0) {
        qk0[node] = red[0][0] + red[1][0] + red[2][0] + red[3][0];
        qk1[node] = red[0][1] + red[1][1] + red[2][1] + red[3][1];
        kq0[node] = red[0][2] + red[1][2] + red[2][2] + red[3][2];
        kq1[node] = red[0][3] + red[1][3] + red[2][3] + red[3][3];
        c0[node] = 0.f;
        c1[node] = 0.f;
    }
}

__global__ void edge_bias_kernel(
    const int* __restrict__ ei, const float* __restrict__ attr,
    const float* __restrict__ qk0, const float* __restrict__ qk1,
    const float* __restrict__ kq0, const float* __restrict__ kq1,
    float* __restrict__ A, int E, int N,
    const float* __restrict__ ibp, const float* __restrict__ imp)
{
    const int e = blockIdx.x * blockDim.x + threadIdx.x;
    if (e >= E) return;
    const int src = ei[e];
    const int dst = ei[E + e];
    const float s = 1.f / (1.f + __expf(-(attr[e] - ibp[0]) * imp[0]));
    const float bias = s * qk0[src] + (1.f - s) * qk1[src]
                     + s * kq0[dst] + (1.f - s) * kq1[dst];
    atomicAdd(&A[(size_t)src * N + dst], bias);
}

// row softmax: read f32 logits, write bf16 probs. N==4096, 256 threads.
__global__ __launch_bounds__(256) void softmax_rows_bf16(
    const float* __restrict__ A, ushort_t* __restrict__ P, int N, float scale)
{
    const int row = blockIdx.x;
    const float* a = A + (size_t)row * N;
    ushort_t* p = P + (size_t)row * N;
    const int t = threadIdx.x;
    float4 vals[4];
    float mx = -1e30f;
    #pragma unroll
    for (int u = 0; u < 4; ++u) {
        float4 vv = ((const float4*)a)[t + u * 256];
        vv.x *= scale; vv.y *= scale; vv.z *= scale; vv.w *= scale;
        vals[u] = vv;
        mx = fmaxf(mx, fmaxf(fmaxf(vv.x, vv.y), fmaxf(vv.z, vv.w)));
    }
    __shared__ float red[4];
    #pragma unroll
    for (int off = 32; off > 0; off >>= 1) mx = fmaxf(mx, __shfl_down(mx, off));
    if ((t & 63) == 0) red[t >> 6] = mx;
    __syncthreads();
    const float m = fmaxf(fmaxf(red[0], red[1]), fmaxf(red[2], red[3]));
    __syncthreads();
    float sum = 0.f;
    #pragma unroll
    for (int u = 0; u < 4; ++u) {
        vals[u].x = __expf(vals[u].x - m);
        vals[u].y = __expf(vals[u].y - m);
        vals[u].z = __expf(vals[u].z - m);
        vals[u].w = __expf(vals[u].w - m);
        sum += vals[u].x + vals[u].y + vals[u].z + vals[u].w;
    }
    #pragma unroll
    for (int off = 32; off > 0; off >>= 1) sum += __shfl_down(sum, off);
    if ((t & 63) == 0) red[t >> 6] = sum;
    __syncthreads();
    const float inv = 1.f / (red[0] + red[1] + red[2] + red[3]);
    #pragma unroll
    for (int u = 0; u < 4; ++u) {
        ushort4v o;
        o[0] = f2bf(vals[u].x * inv);
        o[1] = f2bf(vals[u].y * inv);
        o[2] = f2bf(vals[u].z * inv);
        o[3] = f2bf(vals[u].w * inv);
        ((ushort4v*)p)[t + u * 256] = o;
    }
}

__global__ void edge_coeff_kernel(
    const int* __restrict__ ei, const float* __restrict__ attr,
    const ushort_t* __restrict__ P, float* __restrict__ c0, float* __restrict__ c1,
    int E, int N, const float* __restrict__ ibp, const float* __restrict__ imp)
{
    const int e = blockIdx.x * blockDim.x + threadIdx.x;
    if (e >= E) return;
    const int src = ei[e];
    const int dst = ei[E + e];
    const float s = 1.f / (1.f + __expf(-(attr[e] - ibp[0]) * imp[0]));
    const float pv = bf2f(P[(size_t)src * N + dst]);
    atomicAdd(&c0[src], pv * s);
    atomicAdd(&c1[src], pv * (1.f - s));
}

// ---------------------------------------------------------------------------
extern "C" void kernel_launch(void* const* d_in, const int* in_sizes, int n_in,
                              void* d_out, int out_size, void* d_ws, size_t ws_size,
                              hipStream_t stream)
{
    const float* x    = (const float*)d_in[0];
    const int*   ei   = (const int*)d_in[1];
    const float* attr = (const float*)d_in[2];
    const float* Wk   = (const float*)d_in[3];
    const float* Wq   = (const float*)d_in[4];
    const float* Wv   = (const float*)d_in[5];
    const float* Ek   = (const float*)d_in[6];
    const float* Eq   = (const float*)d_in[7];
    const float* Ev   = (const float*)d_in[8];
    const float* ib   = (const float*)d_in[9];
    const float* im   = (const float*)d_in[10];
    float* out = (float*)d_out;

    const int FEAT = (int)lroundf(sqrtf((float)in_sizes[5]));   // 512
    const int HID  = in_sizes[3] / FEAT;                        // 256
    const int N    = in_sizes[0] / FEAT;                        // 4096
    const int E    = in_sizes[2];                               // 131072

    char* w = (char*)d_ws;
    size_t o = 0;
    ushort_t* xb   = (ushort_t*)(w + o); o += (size_t)N * FEAT * 2;
    ushort_t* Wqkt = (ushort_t*)(w + o); o += (size_t)2 * HID * FEAT * 2;
    ushort_t* Wvt  = (ushort_t*)(w + o); o += (size_t)FEAT * FEAT * 2;
    ushort_t* qkb  = (ushort_t*)(w + o); o += (size_t)N * 2 * HID * 2;
    ushort_t* vTb  = (ushort_t*)(w + o); o += (size_t)FEAT * N * 2;
    float*    Abuf = (float*)(w + o);    o += (size_t)N * N * 4;
    ushort_t* Pb   = (ushort_t*)(w + o); o += (size_t)N * N * 2;
    float*    qk0  = (float*)(w + o);    o += (size_t)N * 4;
    float*    qk1  = (float*)(w + o);    o += (size_t)N * 4;
    float*    kq0  = (float*)(w + o);    o += (size_t)N * 4;
    float*    kq1  = (float*)(w + o);    o += (size_t)N * 4;
    float*    c0   = (float*)(w + o);    o += (size_t)N * 4;
    float*    c1   = (float*)(w + o);    o += (size_t)N * 4;
    int*      cnt  = (int*)(w + o);      o += 128 * 4;
    float*    pvpart = Abuf;   // logits dead after softmax; 4 x 8 MB fits

    const dim3 blk(256);
    const int NZ = 4;
    const int Kchunk = N / NZ;         // 1024

    // prep: x->bf16 + tiled weight transposes + counter zeroing
    const int xBlocks = (N * FEAT / 8) / 256;                       // 1024
    const int qkTiles = (FEAT / 32) * (HID / 32);                   // 128
    const int vTiles  = (FEAT / 32) * (FEAT / 32);                  // 256
    prep_kernel<<<xBlocks + 2 * qkTiles + vTiles, blk, 0, stream>>>(
        x, Wq, Wk, Wv, xb, Wqkt, Wvt, cnt, N, FEAT, HID);

    // both projections, one launch (256 blocks)
    proj_gemm<<<256, blk, 0, stream>>>(xb, Wqkt, Wvt, qkb, vTb, FEAT, HID, N);

    // per-node embedding dots (+ c0/c1 zero)
    node_dots<<<N, blk, 0, stream>>>(qkb, Ek, Eq, qk0, qk1, kq0, kq1, c0, c1, HID);

    // A = 2 * q k^T  (f32)
    gemm_nt_mfma<false><<<dim3(N / 128, N / 128), blk, 0, stream>>>(
        qkb, qkb + HID, Abuf, 2 * HID, 2 * HID, N, HID, 2.f);

    // += per-edge bias
    edge_bias_kernel<<<(E + 255) / 256, blk, 0, stream>>>(ei, attr, qk0, qk1, kq0, kq1,
                                                          Abuf, E, N, ib, im);

    // P = softmax(A / sqrt(FEAT)) -> bf16
    softmax_rows_bf16<<<N, blk, 0, stream>>>(Abuf, Pb, N, 1.f / sqrtf((float)FEAT));

    // edge coefficients
    edge_coeff_kernel<<<(E + 255) / 256, blk, 0, stream>>>(ei, attr, Pb, c0, c1, E, N, ib, im);

    // PV split-K + fused deterministic reduce + rank-2 epilogue
    pv_gemm_splitk<<<dim3(FEAT / 128, N / 128, NZ), blk, 0, stream>>>(
        Pb, vTb, pvpart, out, c0, c1, Ev, cnt, N, FEAT, Kchunk, NZ);
}

// Round 8
// 130.869 us; speedup vs baseline: 1.6723x; 1.6723x over previous
//
#include <hip/hip_runtime.h>
#include <hip/hip_bf16.h>
#include <cmath>

// ---------------------------------------------------------------------------
// DistanceAwareSelfAttentionHead — bf16 MFMA, round 8.
//   - PV: split-K NZ=4, 128^2 tiles, 512 blocks (2/CU), bf16 partials
//     (halved partial traffic) in dead Abuf, separate ordered reduce kernel.
//   - prep: coalesced 32x32 LDS-tiled weight transposes.
//   Ledger: no atomics for split-K (R6), no device-scope fence protocols in
//   hot kernels (R7 — per-XCD L2 flush serializes), 2-phase GEMM needs >=2
//   blocks/CU (R4).
//   9 kernel launches.
// ---------------------------------------------------------------------------

typedef short bf16x8 __attribute__((ext_vector_type(8)));
typedef float f32x4  __attribute__((ext_vector_type(4)));
typedef unsigned short ushort_t;
typedef unsigned short ushort4v __attribute__((ext_vector_type(4)));
typedef unsigned short ushort8v __attribute__((ext_vector_type(8)));

__device__ __forceinline__ ushort_t f2bf(float f) {
    union { float f; unsigned u; } v; v.f = f;
    unsigned u = v.u;
    u += 0x7FFFu + ((u >> 16) & 1u);   // RNE
    return (ushort_t)(u >> 16);
}
__device__ __forceinline__ float bf2f(ushort_t h) {
    union { unsigned u; float f; } v; v.u = ((unsigned)h) << 16;
    return v.f;
}
__device__ __forceinline__ void gload_lds16(const void* g, void* l) {
    __builtin_amdgcn_global_load_lds(
        (const __attribute__((address_space(1))) void*)g,
        (__attribute__((address_space(3))) void*)l, 16, 0, 0);
}

// ---------------------------------------------------------------------------
// 128x128x(BK=32) NT GEMM core: acc[i][j] += sum_k A[bm..][k] * B[bn..][k]
// ---------------------------------------------------------------------------
__device__ __forceinline__ void gemm_core(
    const ushort_t* __restrict__ A, const ushort_t* __restrict__ B,
    int lda, int ldb, int Ksz, size_t kbase, int bm, int bn,
    ushort_t* As, ushort_t* Bs, f32x4 (&acc)[4][4])
{
    constexpr int BK = 32;
    const int tid  = threadIdx.x;
    const int lane = tid & 63;
    const int wid  = tid >> 6;
    const int wm = (wid >> 1) * 64;
    const int wn = (wid & 1) * 64;

    const int r0 = tid >> 2;
    const int c8 = (tid & 3) * 8;
    const ushort_t* Ag0 = A + (size_t)(bm + r0) * lda + kbase + c8;
    const ushort_t* Bg0 = B + (size_t)(bn + r0) * ldb + kbase + c8;
    const ushort_t* Ag1 = Ag0 + (size_t)64 * lda;
    const ushort_t* Bg1 = Bg0 + (size_t)64 * ldb;
    ushort_t* AsW0 = &As[(wid * 64) * 8];
    ushort_t* AsW1 = &As[(256 + wid * 64) * 8];
    ushort_t* BsW0 = &Bs[(wid * 64) * 8];
    ushort_t* BsW1 = &Bs[(256 + wid * 64) * 8];

    const int fr = lane & 15;
    const int kh = (lane >> 4) * 8;

    for (int k0 = 0; k0 < Ksz; k0 += BK) {
        gload_lds16(Ag0 + k0, AsW0);
        gload_lds16(Ag1 + k0, AsW1);
        gload_lds16(Bg0 + k0, BsW0);
        gload_lds16(Bg1 + k0, BsW1);
        __syncthreads();

        bf16x8 af[4], bfv[4];
        #pragma unroll
        for (int i = 0; i < 4; ++i) {
            af[i]  = *(const bf16x8*)&As[(wm + i * 16 + fr) * 32 + kh];
            bfv[i] = *(const bf16x8*)&Bs[(wn + i * 16 + fr) * 32 + kh];
        }
        #pragma unroll
        for (int i = 0; i < 4; ++i)
            #pragma unroll
            for (int j = 0; j < 4; ++j)
                acc[i][j] = __builtin_amdgcn_mfma_f32_16x16x32_bf16(
                    af[i], bfv[j], acc[i][j], 0, 0, 0);
        __syncthreads();
    }
}

__device__ __forceinline__ int swizzle_bid()
{
    int bid = blockIdx.y * gridDim.x + blockIdx.x;
    const int nwg = gridDim.x * gridDim.y;
    if ((nwg & 7) == 0) {
        const int cpx = nwg >> 3;
        bid = (bid & 7) * cpx + (bid >> 3);
    }
    return bid;
}

// general 128x128 GEMM (f32 or bf16 store) — used for S logits GEMM
template<bool STORE_BF16>
__global__ __launch_bounds__(256) void gemm_nt_mfma(
    const ushort_t* __restrict__ A, const ushort_t* __restrict__ B,
    void* __restrict__ Cv, int lda, int ldb, int ldc, int Ksz, float alpha)
{
    __shared__ ushort_t As[128 * 32];
    __shared__ ushort_t Bs[128 * 32];
    const int bid = swizzle_bid();
    const int bm = (bid / gridDim.x) * 128;
    const int bn = (bid % gridDim.x) * 128;
    f32x4 acc[4][4] = {};
    gemm_core(A, B, lda, ldb, Ksz, 0, bm, bn, As, Bs, acc);

    const int lane = threadIdx.x & 63;
    const int wid  = threadIdx.x >> 6;
    const int wm = (wid >> 1) * 64, wn = (wid & 1) * 64;
    const int cr = (lane >> 4) * 4, cc = lane & 15;
    #pragma unroll
    for (int i = 0; i < 4; ++i)
        #pragma unroll
        for (int j = 0; j < 4; ++j) {
            const int col = bn + wn + j * 16 + cc;
            const int rowb = bm + wm + i * 16 + cr;
            #pragma unroll
            for (int jj = 0; jj < 4; ++jj) {
                const float val = alpha * acc[i][j][jj];
                if (STORE_BF16)
                    ((ushort_t*)Cv)[(size_t)(rowb + jj) * ldc + col] = f2bf(val);
                else
                    ((float*)Cv)[(size_t)(rowb + jj) * ldc + col] = val;
            }
        }
}

// both projections in one launch (256 blocks)
__global__ __launch_bounds__(256) void proj_gemm(
    const ushort_t* __restrict__ xb, const ushort_t* __restrict__ Wqkt,
    const ushort_t* __restrict__ Wvt, ushort_t* __restrict__ qkb,
    ushort_t* __restrict__ vTb, int FEAT, int HID, int N)
{
    __shared__ ushort_t As[128 * 32];
    __shared__ ushort_t Bs[128 * 32];
    const int b = blockIdx.x;
    const ushort_t* A; const ushort_t* B; ushort_t* C;
    int bm, bn, ldc;
    if (b < 128) {
        const int gx = (2 * HID) / 128;              // 4
        bm = (b / gx) * 128; bn = (b % gx) * 128;
        A = xb; B = Wqkt; C = qkb; ldc = 2 * HID;
    } else {
        const int b2 = b - 128;
        const int gx = N / 128;                      // 32
        bm = (b2 / gx) * 128; bn = (b2 % gx) * 128;
        A = Wvt; B = xb; C = vTb; ldc = N;
    }
    f32x4 acc[4][4] = {};
    gemm_core(A, B, FEAT, FEAT, FEAT, 0, bm, bn, As, Bs, acc);

    const int lane = threadIdx.x & 63;
    const int wid  = threadIdx.x >> 6;
    const int wm = (wid >> 1) * 64, wn = (wid & 1) * 64;
    const int cr = (lane >> 4) * 4, cc = lane & 15;
    #pragma unroll
    for (int i = 0; i < 4; ++i)
        #pragma unroll
        for (int j = 0; j < 4; ++j) {
            const int col = bn + wn + j * 16 + cc;
            const int rowb = bm + wm + i * 16 + cr;
            #pragma unroll
            for (int jj = 0; jj < 4; ++jj)
                C[(size_t)(rowb + jj) * ldc + col] = f2bf(acc[i][j][jj]);
        }
}

// ---------------------------------------------------------------------------
// PV split-K: parts[z][m][f] (bf16) = sum_{k in chunk z} P[m][k] * vT[f][k]
// Grid (FEAT/128, N/128, NZ) = (4, 32, 4) = 512 blocks (2/CU).
// ---------------------------------------------------------------------------
__global__ __launch_bounds__(256) void pv_gemm_splitk(
    const ushort_t* __restrict__ P, const ushort_t* __restrict__ vT,
    ushort_t* __restrict__ parts, int N, int FEAT, int Kchunk)
{
    __shared__ ushort_t As[128 * 32];
    __shared__ ushort_t Bs[128 * 32];
    const int bid = swizzle_bid();
    const int bm = (bid / gridDim.x) * 128;   // row tile in [0,N)
    const int bn = (bid % gridDim.x) * 128;   // col tile in [0,FEAT)

    f32x4 acc[4][4] = {};
    gemm_core(P, vT, N, N, Kchunk, (size_t)blockIdx.z * Kchunk, bm, bn, As, Bs, acc);

    const int tid = threadIdx.x;
    const int lane = tid & 63;
    const int wid  = tid >> 6;
    const int wm = (wid >> 1) * 64, wn = (wid & 1) * 64;
    const int cr = (lane >> 4) * 4, cc = lane & 15;
    ushort_t* myPart = parts + (size_t)blockIdx.z * N * FEAT;
    #pragma unroll
    for (int i = 0; i < 4; ++i)
        #pragma unroll
        for (int j = 0; j < 4; ++j) {
            const int col = bn + wn + j * 16 + cc;
            const int rowb = bm + wm + i * 16 + cr;
            #pragma unroll
            for (int jj = 0; jj < 4; ++jj)
                myPart[(size_t)(rowb + jj) * FEAT + col] = f2bf(acc[i][j][jj]);
        }
}

// out = sum_z parts[z] (bf16, fixed z order) + c0[i]*Ev0 + c1[i]*Ev1
__global__ void reduce_add_rv_kernel(
    const ushort_t* __restrict__ parts, float* __restrict__ out,
    const float* __restrict__ c0, const float* __restrict__ c1,
    const float* __restrict__ Ev, int FEAT, size_t zstride, int nz)
{
    const int i8 = blockIdx.x * 256 + threadIdx.x;   // 8-elem index
    const int F8 = FEAT / 8;
    const int node = i8 / F8;
    const int f0 = (i8 % F8) * 8;
    float s[8] = {};
    for (int z = 0; z < nz; ++z) {
        const ushort8v p = *(const ushort8v*)(parts + (size_t)z * zstride + (size_t)i8 * 8);
        #pragma unroll
        for (int j = 0; j < 8; ++j) s[j] += bf2f(p[j]);
    }
    const float a0 = c0[node], a1 = c1[node];
    float4 o0, o1;
    const float4 e00 = *(const float4*)(Ev + f0);
    const float4 e01 = *(const float4*)(Ev + f0 + 4);
    const float4 e10 = *(const float4*)(Ev + FEAT + f0);
    const float4 e11 = *(const float4*)(Ev + FEAT + f0 + 4);
    o0.x = s[0] + a0 * e00.x + a1 * e10.x;
    o0.y = s[1] + a0 * e00.y + a1 * e10.y;
    o0.z = s[2] + a0 * e00.z + a1 * e10.z;
    o0.w = s[3] + a0 * e00.w + a1 * e10.w;
    o1.x = s[4] + a0 * e01.x + a1 * e11.x;
    o1.y = s[5] + a0 * e01.y + a1 * e11.y;
    o1.z = s[6] + a0 * e01.z + a1 * e11.z;
    o1.w = s[7] + a0 * e01.w + a1 * e11.w;
    float* op = out + (size_t)node * FEAT + f0;
    *(float4*)op = o0;
    *(float4*)(op + 4) = o1;
}

// ---------------------------------------------------------------------------
// prep: xb = bf16(x) (vectorized); W transposes via coalesced 32x32 LDS tiles.
__global__ __launch_bounds__(256) void prep_kernel(
    const float* __restrict__ x, const float* __restrict__ Wq,
    const float* __restrict__ Wk, const float* __restrict__ Wv,
    ushort_t* __restrict__ xb, ushort_t* __restrict__ Wqkt,
    ushort_t* __restrict__ Wvt, int N, int FEAT, int HID)
{
    const int b = blockIdx.x;
    const int tid = threadIdx.x;
    const int xBlocks = (N * FEAT / 8) / 256;              // 1024
    if (b < xBlocks) {
        const int i = b * 256 + tid;
        const float4 a = ((const float4*)x)[2 * i];
        const float4 c = ((const float4*)x)[2 * i + 1];
        ushort8v o;
        o[0] = f2bf(a.x); o[1] = f2bf(a.y); o[2] = f2bf(a.z); o[3] = f2bf(a.w);
        o[4] = f2bf(c.x); o[5] = f2bf(c.y); o[6] = f2bf(c.z); o[7] = f2bf(c.w);
        ((ushort8v*)xb)[i] = o;
        return;
    }

    // tiled transpose src[I][O] -> dst[O][I], 32x32 tiles
    __shared__ float tile[32][33];
    const int qkTiles = (FEAT / 32) * (HID / 32);          // 128
    int t = b - xBlocks;
    const float* src; ushort_t* dst; int I, O;
    if (t < qkTiles)            { src = Wq; dst = Wqkt;                       I = FEAT; O = HID; }
    else if (t < 2 * qkTiles)   { src = Wk; dst = Wqkt + (size_t)HID * FEAT;  I = FEAT; O = HID; t -= qkTiles; }
    else                        { src = Wv; dst = Wvt;                        I = FEAT; O = FEAT; t -= 2 * qkTiles; }
    const int ot = O / 32;
    const int r0 = (t / ot) * 32;   // i-offset
    const int c0 = (t % ot) * 32;   // o-offset
    const int lr = tid >> 5;        // 0..7
    const int lc = tid & 31;        // 0..31
    #pragma unroll
    for (int rr = 0; rr < 32; rr += 8)
        tile[lr + rr][lc] = src[(size_t)(r0 + lr + rr) * O + c0 + lc];
    __syncthreads();
    #pragma unroll
    for (int rr = 0; rr < 32; rr += 8)
        dst[(size_t)(c0 + lr + rr) * I + r0 + lc] = f2bf(tile[lc][lr + rr]);
}

// per-node dots from merged qk buffer; also zeroes c0/c1
__global__ __launch_bounds__(256) void node_dots(
    const ushort_t* __restrict__ qk,
    const float* __restrict__ Ek, const float* __restrict__ Eq,
    float* qk0, float* qk1, float* kq0, float* kq1,
    float* c0, float* c1, int HID)
{
    const int node = blockIdx.x;
    const int t = threadIdx.x;   // == HID == 256
    const ushort_t* row = qk + (size_t)node * (2 * HID);
    const float qv = bf2f(row[t]);
    const float kv = bf2f(row[HID + t]);
    float p0 = qv * Ek[t];
    float p1 = qv * Ek[HID + t];
    float p2 = kv * Eq[t];
    float p3 = kv * Eq[HID + t];
    #pragma unroll
    for (int off = 32; off > 0; off >>= 1) {
        p0 += __shfl_down(p0, off);
        p1 += __shfl_down(p1, off);
        p2 += __shfl_down(p2, off);
        p3 += __shfl_down(p3, off);
    }
    __shared__ float red[4][4];
    if ((t & 63) == 0) {
        const int w = t >> 6;
        red[w][0] = p0; red[w][1] = p1; red[w][2] = p2; red[w][3] = p3;
    }
    __syncthreads();
    if (t == 0) {
        qk0[node] = red[0][0] + red[1][0] + red[2][0] + red[3][0];
        qk1[node] = red[0][1] + red[1][1] + red[2][1] + red[3][1];
        kq0[node] = red[0][2] + red[1][2] + red[2][2] + red[3][2];
        kq1[node] = red[0][3] + red[1][3] + red[2][3] + red[3][3];
        c0[node] = 0.f;
        c1[node] = 0.f;
    }
}

__global__ void edge_bias_kernel(
    const int* __restrict__ ei, const float* __restrict__ attr,
    const float* __restrict__ qk0, const float* __restrict__ qk1,
    const float* __restrict__ kq0, const float* __restrict__ kq1,
    float* __restrict__ A, int E, int N,
    const float* __restrict__ ibp, const float* __restrict__ imp)
{
    const int e = blockIdx.x * blockDim.x + threadIdx.x;
    if (e >= E) return;
    const int src = ei[e];
    const int dst = ei[E + e];
    const float s = 1.f / (1.f + __expf(-(attr[e] - ibp[0]) * imp[0]));
    const float bias = s * qk0[src] + (1.f - s) * qk1[src]
                     + s * kq0[dst] + (1.f - s) * kq1[dst];
    atomicAdd(&A[(size_t)src * N + dst], bias);
}

// row softmax: read f32 logits, write bf16 probs. N==4096, 256 threads.
__global__ __launch_bounds__(256) void softmax_rows_bf16(
    const float* __restrict__ A, ushort_t* __restrict__ P, int N, float scale)
{
    const int row = blockIdx.x;
    const float* a = A + (size_t)row * N;
    ushort_t* p = P + (size_t)row * N;
    const int t = threadIdx.x;
    float4 vals[4];
    float mx = -1e30f;
    #pragma unroll
    for (int u = 0; u < 4; ++u) {
        float4 vv = ((const float4*)a)[t + u * 256];
        vv.x *= scale; vv.y *= scale; vv.z *= scale; vv.w *= scale;
        vals[u] = vv;
        mx = fmaxf(mx, fmaxf(fmaxf(vv.x, vv.y), fmaxf(vv.z, vv.w)));
    }
    __shared__ float red[4];
    #pragma unroll
    for (int off = 32; off > 0; off >>= 1) mx = fmaxf(mx, __shfl_down(mx, off));
    if ((t & 63) == 0) red[t >> 6] = mx;
    __syncthreads();
    const float m = fmaxf(fmaxf(red[0], red[1]), fmaxf(red[2], red[3]));
    __syncthreads();
    float sum = 0.f;
    #pragma unroll
    for (int u = 0; u < 4; ++u) {
        vals[u].x = __expf(vals[u].x - m);
        vals[u].y = __expf(vals[u].y - m);
        vals[u].z = __expf(vals[u].z - m);
        vals[u].w = __expf(vals[u].w - m);
        sum += vals[u].x + vals[u].y + vals[u].z + vals[u].w;
    }
    #pragma unroll
    for (int off = 32; off > 0; off >>= 1) sum += __shfl_down(sum, off);
    if ((t & 63) == 0) red[t >> 6] = sum;
    __syncthreads();
    const float inv = 1.f / (red[0] + red[1] + red[2] + red[3]);
    #pragma unroll
    for (int u = 0; u < 4; ++u) {
        ushort4v o;
        o[0] = f2bf(vals[u].x * inv);
        o[1] = f2bf(vals[u].y * inv);
        o[2] = f2bf(vals[u].z * inv);
        o[3] = f2bf(vals[u].w * inv);
        ((ushort4v*)p)[t + u * 256] = o;
    }
}

__global__ void edge_coeff_kernel(
    const int* __restrict__ ei, const float* __restrict__ attr,
    const ushort_t* __restrict__ P, float* __restrict__ c0, float* __restrict__ c1,
    int E, int N, const float* __restrict__ ibp, const float* __restrict__ imp)
{
    const int e = blockIdx.x * blockDim.x + threadIdx.x;
    if (e >= E) return;
    const int src = ei[e];
    const int dst = ei[E + e];
    const float s = 1.f / (1.f + __expf(-(attr[e] - ibp[0]) * imp[0]));
    const float pv = bf2f(P[(size_t)src * N + dst]);
    atomicAdd(&c0[src], pv * s);
    atomicAdd(&c1[src], pv * (1.f - s));
}

// ---------------------------------------------------------------------------
extern "C" void kernel_launch(void* const* d_in, const int* in_sizes, int n_in,
                              void* d_out, int out_size, void* d_ws, size_t ws_size,
                              hipStream_t stream)
{
    const float* x    = (const float*)d_in[0];
    const int*   ei   = (const int*)d_in[1];
    const float* attr = (const float*)d_in[2];
    const float* Wk   = (const float*)d_in[3];
    const float* Wq   = (const float*)d_in[4];
    const float* Wv   = (const float*)d_in[5];
    const float* Ek   = (const float*)d_in[6];
    const float* Eq   = (const float*)d_in[7];
    const float* Ev   = (const float*)d_in[8];
    const float* ib   = (const float*)d_in[9];
    const float* im   = (const float*)d_in[10];
    float* out = (float*)d_out;

    const int FEAT = (int)lroundf(sqrtf((float)in_sizes[5]));   // 512
    const int HID  = in_sizes[3] / FEAT;                        // 256
    const int N    = in_sizes[0] / FEAT;                        // 4096
    const int E    = in_sizes[2];                               // 131072

    char* w = (char*)d_ws;
    size_t o = 0;
    ushort_t* xb   = (ushort_t*)(w + o); o += (size_t)N * FEAT * 2;
    ushort_t* Wqkt = (ushort_t*)(w + o); o += (size_t)2 * HID * FEAT * 2;
    ushort_t* Wvt  = (ushort_t*)(w + o); o += (size_t)FEAT * FEAT * 2;
    ushort_t* qkb  = (ushort_t*)(w + o); o += (size_t)N * 2 * HID * 2;
    ushort_t* vTb  = (ushort_t*)(w + o); o += (size_t)FEAT * N * 2;
    float*    Abuf = (float*)(w + o);    o += (size_t)N * N * 4;
    ushort_t* Pb   = (ushort_t*)(w + o); o += (size_t)N * N * 2;
    float*    qk0  = (float*)(w + o);    o += (size_t)N * 4;
    float*    qk1  = (float*)(w + o);    o += (size_t)N * 4;
    float*    kq0  = (float*)(w + o);    o += (size_t)N * 4;
    float*    kq1  = (float*)(w + o);    o += (size_t)N * 4;
    float*    c0   = (float*)(w + o);    o += (size_t)N * 4;
    float*    c1   = (float*)(w + o);    o += (size_t)N * 4;
    ushort_t* pvpart = (ushort_t*)Abuf;  // logits dead after softmax; 4x4MB bf16

    const dim3 blk(256);
    const int NZ = 4;
    const int Kchunk = N / NZ;         // 1024

    // prep: x->bf16 + tiled weight transposes
    const int xBlocks = (N * FEAT / 8) / 256;                       // 1024
    const int qkTiles = (FEAT / 32) * (HID / 32);                   // 128
    const int vTiles  = (FEAT / 32) * (FEAT / 32);                  // 256
    prep_kernel<<<xBlocks + 2 * qkTiles + vTiles, blk, 0, stream>>>(
        x, Wq, Wk, Wv, xb, Wqkt, Wvt, N, FEAT, HID);

    // both projections, one launch (256 blocks)
    proj_gemm<<<256, blk, 0, stream>>>(xb, Wqkt, Wvt, qkb, vTb, FEAT, HID, N);

    // per-node embedding dots (+ c0/c1 zero)
    node_dots<<<N, blk, 0, stream>>>(qkb, Ek, Eq, qk0, qk1, kq0, kq1, c0, c1, HID);

    // A = 2 * q k^T  (f32)
    gemm_nt_mfma<false><<<dim3(N / 128, N / 128), blk, 0, stream>>>(
        qkb, qkb + HID, Abuf, 2 * HID, 2 * HID, N, HID, 2.f);

    // += per-edge bias
    edge_bias_kernel<<<(E + 255) / 256, blk, 0, stream>>>(ei, attr, qk0, qk1, kq0, kq1,
                                                          Abuf, E, N, ib, im);

    // P = softmax(A / sqrt(FEAT)) -> bf16
    softmax_rows_bf16<<<N, blk, 0, stream>>>(Abuf, Pb, N, 1.f / sqrtf((float)FEAT));

    // edge coefficients
    edge_coeff_kernel<<<(E + 255) / 256, blk, 0, stream>>>(ei, attr, Pb, c0, c1, E, N, ib, im);

    // PV split-K (bf16 partials into dead Abuf)
    pv_gemm_splitk<<<dim3(FEAT / 128, N / 128, NZ), blk, 0, stream>>>(
        Pb, vTb, pvpart, N, FEAT, Kchunk);

    // out = sum_z partials + c0[i]*Ev0 + c1[i]*Ev1
    reduce_add_rv_kernel<<<(N * FEAT / 8) / 256, blk, 0, stream>>>(
        pvpart, out, c0, c1, Ev, FEAT, (size_t)N * FEAT, NZ);
}